// Round 5
// baseline (2915.133 us; speedup 1.0000x reference)
//
#include <hip/hip_runtime.h>
#include <hip/hip_bf16.h>
#include <math.h>

typedef short s16x8 __attribute__((ext_vector_type(8)));
typedef float f32x4 __attribute__((ext_vector_type(4)));
typedef __hip_bfloat16 bf16;

#define NTOK 4096
#define S_LEN 2048
#define HID_C 1024
#define E_C 8
#define INTER_C 2816
#define WIN_C 64
#define CAP 4096
#define OUT0_N ((size_t)NTOK*HID_C)

static __device__ __forceinline__ float b2f(bf16 v){ return __bfloat162float(v); }
static __device__ __forceinline__ bf16  f2b(float v){ return __float2bfloat16(v); }
static __device__ __forceinline__ short f2bs(float v){ bf16 h = __float2bfloat16(v); return *reinterpret_cast<short*>(&h); }
struct SplitBF { short hi; short lo; };
static __device__ __forceinline__ SplitBF splitf(float x){
    SplitBF r;
    bf16 bh = __float2bfloat16(x);
    r.hi = *reinterpret_cast<short*>(&bh);
    float rem = x - __bfloat162float(bh);
    bf16 bl = __float2bfloat16(rem);
    r.lo = *reinterpret_cast<short*>(&bl);
    return r;
}

// ---------------- RMSNorm (f32 in, f32 out; optionally also bf16 out) ----------------
template<bool ALSO_BF16>
__global__ __launch_bounds__(256) void rmsnorm_k(const float* __restrict__ xin,
                                                 const float* __restrict__ w,
                                                 float* __restrict__ outf,
                                                 bf16* __restrict__ outb){
    const int t = blockIdx.x, tid = threadIdx.x;
    float4 v = *(const float4*)(xin + (size_t)t*HID_C + tid*4);
    float x[4] = {v.x, v.y, v.z, v.w};
    float s = x[0]*x[0]+x[1]*x[1]+x[2]*x[2]+x[3]*x[3];
    #pragma unroll
    for (int off=32; off; off>>=1) s += __shfl_xor(s, off);
    __shared__ float red[4];
    if ((tid&63)==0) red[tid>>6] = s;
    __syncthreads();
    float tot = red[0]+red[1]+red[2]+red[3];
    float sc = rsqrtf(tot*(1.0f/HID_C) + 1e-8f);
    float4 wv = *(const float4*)(w + tid*4);
    float o[4] = { x[0]*sc*wv.x, x[1]*sc*wv.y, x[2]*sc*wv.z, x[3]*sc*wv.w };
    *(float4*)(outf + (size_t)t*HID_C + tid*4) = make_float4(o[0],o[1],o[2],o[3]);
    if (ALSO_BF16){
        __align__(8) bf16 tmp[4] = { f2b(o[0]), f2b(o[1]), f2b(o[2]), f2b(o[3]) };
        *(uint2*)(outb + (size_t)t*HID_C + tid*4) = *(uint2*)tmp;
    }
}

// ------- split-bf16 f32-accurate GEMM: C = A@B (+resid), 128x128 tile, BK=32 -------
// A,B,C,resid all f32. acc = hi*hi + hi*lo + lo*hi  (error ~2^-18 relative)
template<bool RESID>
__global__ __launch_bounds__(256) void sgemm_k(const float* __restrict__ A,
                                               const float* __restrict__ B,
                                               float* __restrict__ C,
                                               const float* __restrict__ resid,
                                               int N, int K){
    __shared__ __align__(16) short lAh[128*40];
    __shared__ __align__(16) short lAl[128*40];
    __shared__ __align__(16) short lBh[128*40];
    __shared__ __align__(16) short lBl[128*40];
    const int tid = threadIdx.x;
    const int bm0 = blockIdx.x*128, bn0 = blockIdx.y*128;
    const int l = tid & 63, w = tid >> 6, wr = w >> 1, wc = w & 1;
    f32x4 acc[4][4] = {};
    for (int kt = 0; kt < K/32; ++kt){
        #pragma unroll
        for (int i = 0; i < 4; ++i){          // A: 128 rows x 32 k
            int u = tid + i*256;
            int r = u >> 3, c4 = (u & 7)*4;
            float4 v = *(const float4*)(A + (size_t)(bm0+r)*K + kt*32 + c4);
            SplitBF s0 = splitf(v.x), s1 = splitf(v.y), s2 = splitf(v.z), s3 = splitf(v.w);
            __align__(8) short hv[4] = { s0.hi, s1.hi, s2.hi, s3.hi };
            __align__(8) short lv[4] = { s0.lo, s1.lo, s2.lo, s3.lo };
            *(uint2*)(&lAh[r*40 + c4]) = *(uint2*)hv;
            *(uint2*)(&lAl[r*40 + c4]) = *(uint2*)lv;
        }
        #pragma unroll
        for (int i = 0; i < 4; ++i){          // B: 32 k-rows x 128 n, store transposed [n][k]
            int u = tid + i*256;
            int k = u >> 5, n0 = (u & 31)*4;
            float4 v = *(const float4*)(B + (size_t)(kt*32 + k)*N + bn0 + n0);
            SplitBF s0 = splitf(v.x), s1 = splitf(v.y), s2 = splitf(v.z), s3 = splitf(v.w);
            lBh[(n0+0)*40+k]=s0.hi; lBh[(n0+1)*40+k]=s1.hi; lBh[(n0+2)*40+k]=s2.hi; lBh[(n0+3)*40+k]=s3.hi;
            lBl[(n0+0)*40+k]=s0.lo; lBl[(n0+1)*40+k]=s1.lo; lBl[(n0+2)*40+k]=s2.lo; lBl[(n0+3)*40+k]=s3.lo;
        }
        __syncthreads();
        s16x8 ah[4], al[4], bh[4], bl[4];
        #pragma unroll
        for (int mi = 0; mi < 4; ++mi){
            int r = wr*64 + mi*16 + (l&15);
            ah[mi] = *(const s16x8*)(&lAh[r*40 + (l>>4)*8]);
            al[mi] = *(const s16x8*)(&lAl[r*40 + (l>>4)*8]);
        }
        #pragma unroll
        for (int ni = 0; ni < 4; ++ni){
            int n = wc*64 + ni*16 + (l&15);
            bh[ni] = *(const s16x8*)(&lBh[n*40 + (l>>4)*8]);
            bl[ni] = *(const s16x8*)(&lBl[n*40 + (l>>4)*8]);
        }
        #pragma unroll
        for (int mi = 0; mi < 4; ++mi)
            #pragma unroll
            for (int ni = 0; ni < 4; ++ni){
                acc[mi][ni] = __builtin_amdgcn_mfma_f32_16x16x32_bf16(ah[mi], bh[ni], acc[mi][ni], 0,0,0);
                acc[mi][ni] = __builtin_amdgcn_mfma_f32_16x16x32_bf16(ah[mi], bl[ni], acc[mi][ni], 0,0,0);
                acc[mi][ni] = __builtin_amdgcn_mfma_f32_16x16x32_bf16(al[mi], bh[ni], acc[mi][ni], 0,0,0);
            }
        __syncthreads();
    }
    #pragma unroll
    for (int mi = 0; mi < 4; ++mi)
        #pragma unroll
        for (int ni = 0; ni < 4; ++ni)
            #pragma unroll
            for (int rr = 0; rr < 4; ++rr){
                int row = bm0 + wr*64 + mi*16 + (l>>4)*4 + rr;
                int col = bn0 + wc*64 + ni*16 + (l&15);
                float vv = acc[mi][ni][rr];
                if (RESID) vv += resid[(size_t)row*N + col];
                C[(size_t)row*N + col] = vv;
            }
}

// ---------------- RoPE f32 (in-place on q and k) ----------------
__global__ __launch_bounds__(256) void rope_k(float* __restrict__ qb, float* __restrict__ kb,
                                              const float* __restrict__ cosb, const float* __restrict__ sinb){
    int idx = blockIdx.x*256 + threadIdx.x;      // 4096 * 640 total
    int t = idx / 640;
    int r = idx - t*640;
    int hs = r >> 5, tp = r & 31;
    int s = t & (S_LEN-1);
    float c  = cosb[s*32+tp];
    float sn = sinb[s*32+tp];
    float* base;
    if (hs < 16) base = qb + (size_t)t*1024 + hs*64 + 2*tp;
    else         base = kb + (size_t)t*256 + (hs-16)*64 + 2*tp;
    float2 v = *(float2*)base;
    *(float2*)base = make_float2(v.x*c - v.y*sn, v.x*sn + v.y*c);
}

// ---------------- sliding-window GQA attention f32: 1 wave per (token, head) ----------------
__global__ __launch_bounds__(64) void attn_k(const float* __restrict__ qb, const float* __restrict__ kb,
                                             const float* __restrict__ vb, float* __restrict__ ob){
    const int l = threadIdx.x;
    const int bs = blockIdx.x;               // b*S + s
    const int h = blockIdx.y, hk = h >> 2;
    const int sq = bs & (S_LEN-1);
    __shared__ float qs[64];
    __shared__ float ps[65];
    qs[l] = qb[(size_t)bs*1024 + h*64 + l];
    __syncthreads();
    const int j0 = (sq - WIN_C) > 0 ? (sq - WIN_C) : 0;
    const int nk = sq - j0 + 1;              // <= 65
    const int tokbase = bs - sq;             // b*S
    float sc[2] = {-1e9f, -1e9f};
    #pragma unroll
    for (int it = 0; it < 2; ++it){
        int jj = l + it*64;
        if (jj < nk){
            const float* kp = kb + (size_t)(tokbase + j0 + jj)*256 + hk*64;
            float d = 0.f;
            #pragma unroll
            for (int c = 0; c < 16; ++c){
                float4 kv = *(const float4*)(kp + c*4);
                d += qs[c*4+0]*kv.x + qs[c*4+1]*kv.y + qs[c*4+2]*kv.z + qs[c*4+3]*kv.w;
            }
            sc[it] = d*0.125f;               // 1/sqrt(64)
        }
    }
    float m = fmaxf(sc[0], sc[1]);
    #pragma unroll
    for (int off=32; off; off>>=1) m = fmaxf(m, __shfl_xor(m, off));
    float e0 = (l      < nk) ? __expf(sc[0]-m) : 0.f;
    float e1 = (l + 64 < nk) ? __expf(sc[1]-m) : 0.f;
    float s = e0 + e1;
    #pragma unroll
    for (int off=32; off; off>>=1) s += __shfl_xor(s, off);
    float inv = 1.f/s;
    if (l      < nk) ps[l]    = e0*inv;
    if (l + 64 < nk) ps[l+64] = e1*inv;
    __syncthreads();
    float acc = 0.f;
    for (int jj = 0; jj < nk; ++jj)
        acc += ps[jj]*vb[(size_t)(tokbase + j0 + jj)*256 + hk*64 + l];
    ob[(size_t)bs*1024 + h*64 + l] = acc;
}

// ---------------- router f32: 1 wave per token ----------------
__global__ __launch_bounds__(64) void router_k(const float* __restrict__ h2f, const float* __restrict__ rw,
                                               int* __restrict__ lists, float* __restrict__ wl,
                                               int* __restrict__ cnt, float* __restrict__ psum){
    const int t = blockIdx.x, l = threadIdx.x;
    float lg[8] = {0,0,0,0,0,0,0,0};
    for (int c = 0; c < 16; ++c){
        int kidx = l + c*64;
        float x = h2f[(size_t)t*HID_C + kidx];
        float4 w0 = *(const float4*)(rw + (size_t)kidx*8);
        float4 w1 = *(const float4*)(rw + (size_t)kidx*8 + 4);
        lg[0] += x*w0.x; lg[1] += x*w0.y; lg[2] += x*w0.z; lg[3] += x*w0.w;
        lg[4] += x*w1.x; lg[5] += x*w1.y; lg[6] += x*w1.z; lg[7] += x*w1.w;
    }
    #pragma unroll
    for (int e = 0; e < 8; ++e)
        #pragma unroll
        for (int off=32; off; off>>=1) lg[e] += __shfl_xor(lg[e], off);
    if (l == 0){
        float m = lg[0];
        #pragma unroll
        for (int e = 1; e < 8; ++e) m = fmaxf(m, lg[e]);
        float p[8]; float s = 0.f;
        #pragma unroll
        for (int e = 0; e < 8; ++e){ p[e] = __expf(lg[e]-m); s += p[e]; }
        float invs = 1.f/s;
        #pragma unroll
        for (int e = 0; e < 8; ++e){ p[e] *= invs; atomicAdd(&psum[e], p[e]); }
        float best = -1e30f, sec = -1e30f; int bi = 0, si = 0;
        #pragma unroll
        for (int e = 0; e < 8; ++e){
            float pv = p[e];
            if (pv > best){ sec = best; si = bi; best = pv; bi = e; }
            else if (pv > sec){ sec = pv; si = e; }
        }
        float wsum = best + sec + 1e-9f;
        int s0 = atomicAdd(&cnt[bi], 1);
        lists[bi*CAP + s0] = t; wl[bi*CAP + s0] = best/wsum;
        int s1 = atomicAdd(&cnt[si], 1);
        lists[si*CAP + s1] = t; wl[si*CAP + s1] = sec/wsum;
    }
}

__global__ void finalize_k(const int* __restrict__ cnt, const float* __restrict__ psum,
                           int* __restrict__ offs, float* __restrict__ out){
    if (threadIdx.x == 0 && blockIdx.x == 0){
        int o = 0; float loss = 0.f;
        for (int e = 0; e < 8; ++e){
            offs[e] = o; o += cnt[e];
            loss += (psum[e]*(1.0f/NTOK)) * ((float)cnt[e]*(1.0f/NTOK));
        }
        offs[8] = o;
        out[OUT0_N] = loss * (float)E_C * 0.01f;
    }
}

// ---------------- MoE gate/up fused GEMM (gathered rows), 128x64 tile, weights f32->bf16 ----------------
__global__ __launch_bounds__(256) void moe_mlp1_k(const bf16* __restrict__ h2b,
                                                  const float* __restrict__ gateW,
                                                  const float* __restrict__ upW,
                                                  bf16* __restrict__ inter,
                                                  const int* __restrict__ lists,
                                                  const int* __restrict__ cnt,
                                                  const int* __restrict__ offs){
    const int e = blockIdx.z;
    const int ne = cnt[e];
    const int bm0 = blockIdx.x*128;
    if (bm0 >= ne) return;
    const int bn0 = blockIdx.y*64;
    __shared__ __align__(16) short lA[128*72];
    __shared__ __align__(16) short lG[64*72];
    __shared__ __align__(16) short lU[64*72];
    const int tid = threadIdx.x;
    const int l = tid & 63, w = tid >> 6, wr = w >> 1, wc = w & 1;
    const size_t ebase = (size_t)e*HID_C*INTER_C;
    f32x4 ag[4][2] = {}; f32x4 au[4][2] = {};
    for (int kt = 0; kt < HID_C/64; ++kt){
        #pragma unroll
        for (int i = 0; i < 4; ++i){
            int u = tid + i*256;
            int r = u >> 3, cu = u & 7;
            int slot = bm0 + r;
            s16x8 v = {};
            if (slot < ne){
                int tok = lists[e*CAP + slot];
                v = *(const s16x8*)(h2b + (size_t)tok*HID_C + kt*64 + cu*8);
            }
            *(s16x8*)(&lA[r*72 + cu*8]) = v;
        }
        #pragma unroll
        for (int i = 0; i < 2; ++i){
            int u = tid + i*256;
            int k = u >> 3, n0 = (u & 7)*8;
            size_t gidx = ebase + (size_t)(kt*64 + k)*INTER_C + bn0 + n0;
            const float* gp = gateW + gidx;
            const float* up = upW + gidx;
            float4 ga = *(const float4*)gp, gb = *(const float4*)(gp+4);
            float4 ua = *(const float4*)up, ub = *(const float4*)(up+4);
            lG[(n0+0)*72+k]=f2bs(ga.x); lG[(n0+1)*72+k]=f2bs(ga.y); lG[(n0+2)*72+k]=f2bs(ga.z); lG[(n0+3)*72+k]=f2bs(ga.w);
            lG[(n0+4)*72+k]=f2bs(gb.x); lG[(n0+5)*72+k]=f2bs(gb.y); lG[(n0+6)*72+k]=f2bs(gb.z); lG[(n0+7)*72+k]=f2bs(gb.w);
            lU[(n0+0)*72+k]=f2bs(ua.x); lU[(n0+1)*72+k]=f2bs(ua.y); lU[(n0+2)*72+k]=f2bs(ua.z); lU[(n0+3)*72+k]=f2bs(ua.w);
            lU[(n0+4)*72+k]=f2bs(ub.x); lU[(n0+5)*72+k]=f2bs(ub.y); lU[(n0+6)*72+k]=f2bs(ub.z); lU[(n0+7)*72+k]=f2bs(ub.w);
        }
        __syncthreads();
        #pragma unroll
        for (int kk = 0; kk < 64; kk += 32){
            s16x8 af[4], bg[2], bu[2];
            #pragma unroll
            for (int mi = 0; mi < 4; ++mi)
                af[mi] = *(const s16x8*)(&lA[(wr*64 + mi*16 + (l&15))*72 + kk + (l>>4)*8]);
            #pragma unroll
            for (int ni = 0; ni < 2; ++ni){
                int n = wc*32 + ni*16 + (l&15);
                bg[ni] = *(const s16x8*)(&lG[n*72 + kk + (l>>4)*8]);
                bu[ni] = *(const s16x8*)(&lU[n*72 + kk + (l>>4)*8]);
            }
            #pragma unroll
            for (int mi = 0; mi < 4; ++mi)
                #pragma unroll
                for (int ni = 0; ni < 2; ++ni){
                    ag[mi][ni] = __builtin_amdgcn_mfma_f32_16x16x32_bf16(af[mi], bg[ni], ag[mi][ni], 0,0,0);
                    au[mi][ni] = __builtin_amdgcn_mfma_f32_16x16x32_bf16(af[mi], bu[ni], au[mi][ni], 0,0,0);
                }
        }
        __syncthreads();
    }
    const int obase = offs[e];
    #pragma unroll
    for (int mi = 0; mi < 4; ++mi)
        #pragma unroll
        for (int ni = 0; ni < 2; ++ni)
            #pragma unroll
            for (int rr = 0; rr < 4; ++rr){
                int slot = bm0 + wr*64 + mi*16 + (l>>4)*4 + rr;
                if (slot < ne){
                    int col = bn0 + wc*32 + ni*16 + (l&15);
                    float g = ag[mi][ni][rr], uu = au[mi][ni][rr];
                    float val = (g/(1.f+__expf(-g)))*uu;       // silu(g)*u
                    inter[(size_t)(obase+slot)*INTER_C + col] = f2b(val);
                }
            }
}

// ---------------- MoE down GEMM (K=2816), atomic-accumulate weighted into hres ----------------
__global__ __launch_bounds__(256) void moe_mlp2_k(const bf16* __restrict__ inter,
                                                  const float* __restrict__ downW,
                                                  float* __restrict__ hres,
                                                  const float* __restrict__ wl,
                                                  const int* __restrict__ lists,
                                                  const int* __restrict__ cnt,
                                                  const int* __restrict__ offs){
    const int e = blockIdx.z;
    const int ne = cnt[e];
    const int bm0 = blockIdx.x*128;
    if (bm0 >= ne) return;
    const int bn0 = blockIdx.y*128;
    __shared__ __align__(16) short lA[128*72];
    __shared__ __align__(16) short lB[128*72];
    const int tid = threadIdx.x;
    const int l = tid & 63, w = tid >> 6, wr = w >> 1, wc = w & 1;
    const int obase = offs[e];
    const size_t ebase = (size_t)e*INTER_C*HID_C;
    f32x4 acc[4][4] = {};
    for (int kt = 0; kt < INTER_C/64; ++kt){
        #pragma unroll
        for (int i = 0; i < 4; ++i){
            int u = tid + i*256;
            int r = u >> 3, cu = u & 7;
            int slot = bm0 + r;
            s16x8 v = {};
            if (slot < ne)
                v = *(const s16x8*)(inter + (size_t)(obase + slot)*INTER_C + kt*64 + cu*8);
            *(s16x8*)(&lA[r*72 + cu*8]) = v;
        }
        #pragma unroll
        for (int i = 0; i < 4; ++i){
            int u = tid + i*256;
            int k = u >> 4, n0 = (u & 15)*8;
            const float* bp = downW + ebase + (size_t)(kt*64 + k)*HID_C + bn0 + n0;
            float4 a = *(const float4*)bp, b = *(const float4*)(bp+4);
            lB[(n0+0)*72+k]=f2bs(a.x); lB[(n0+1)*72+k]=f2bs(a.y); lB[(n0+2)*72+k]=f2bs(a.z); lB[(n0+3)*72+k]=f2bs(a.w);
            lB[(n0+4)*72+k]=f2bs(b.x); lB[(n0+5)*72+k]=f2bs(b.y); lB[(n0+6)*72+k]=f2bs(b.z); lB[(n0+7)*72+k]=f2bs(b.w);
        }
        __syncthreads();
        #pragma unroll
        for (int kk = 0; kk < 64; kk += 32){
            s16x8 af[4], bfr[4];
            #pragma unroll
            for (int mi = 0; mi < 4; ++mi)
                af[mi] = *(const s16x8*)(&lA[(wr*64 + mi*16 + (l&15))*72 + kk + (l>>4)*8]);
            #pragma unroll
            for (int ni = 0; ni < 4; ++ni){
                int n = wc*64 + ni*16 + (l&15);
                bfr[ni] = *(const s16x8*)(&lB[n*72 + kk + (l>>4)*8]);
            }
            #pragma unroll
            for (int mi = 0; mi < 4; ++mi)
                #pragma unroll
                for (int ni = 0; ni < 4; ++ni)
                    acc[mi][ni] = __builtin_amdgcn_mfma_f32_16x16x32_bf16(af[mi], bfr[ni], acc[mi][ni], 0,0,0);
        }
        __syncthreads();
    }
    #pragma unroll
    for (int mi = 0; mi < 4; ++mi)
        #pragma unroll
        for (int ni = 0; ni < 4; ++ni)
            #pragma unroll
            for (int rr = 0; rr < 4; ++rr){
                int slot = bm0 + wr*64 + mi*16 + (l>>4)*4 + rr;
                if (slot < ne){
                    int col = bn0 + wc*64 + ni*16 + (l&15);
                    int tok = lists[e*CAP + slot];
                    float wgt = wl[e*CAP + slot];
                    atomicAdd(&hres[(size_t)tok*HID_C + col], acc[mi][ni][rr]*wgt);
                }
            }
}

// ---------------- final: out(f32) = hres  (hres = resid + attn_out + moe_out) ----------------
__global__ __launch_bounds__(256) void final_k(const float* __restrict__ hres,
                                               float* __restrict__ out){
    const int t = blockIdx.x, c = threadIdx.x*4;
    float4 hv = *(const float4*)(hres + (size_t)t*HID_C + c);
    *(float4*)(out + (size_t)t*HID_C + c) = hv;
}

extern "C" void kernel_launch(void* const* d_in, const int* in_sizes, int n_in,
                              void* d_out, int out_size, void* d_ws, size_t ws_size,
                              hipStream_t stream){
    const float* hidden  = (const float*)d_in[0];
    const float* fcos    = (const float*)d_in[1];
    const float* fsin    = (const float*)d_in[2];
    const float* wq      = (const float*)d_in[3];
    const float* wk      = (const float*)d_in[4];
    const float* wv      = (const float*)d_in[5];
    const float* wo      = (const float*)d_in[6];
    const float* routerw = (const float*)d_in[7];
    const float* gatew   = (const float*)d_in[8];
    const float* upw     = (const float*)d_in[9];
    const float* downw   = (const float*)d_in[10];
    const float* n1w     = (const float*)d_in[11];
    const float* n2w     = (const float*)d_in[12];

    char* p = (char*)d_ws;
    size_t off = 0;
    auto alloc = [&](size_t b)->void*{ void* r = p + off; off = (off + b + 255) & ~(size_t)255; return r; };
    // small control buffers FIRST
    int*   cnt   = (int*)alloc(64);
    float* psum  = (float*)alloc(64);
    int*   offs  = (int*)alloc(64);
    int*   lists = (int*)alloc((size_t)E_C*CAP*4);
    float* wl    = (float*)alloc((size_t)E_C*CAP*4);
    // large buffers (f32 attention path)
    float* h1    = (float*)alloc((size_t)NTOK*HID_C*4);      // norm1 out; later attn out
    float* qb    = (float*)alloc((size_t)NTOK*HID_C*4);      // q; later h2f
    float* kb    = (float*)alloc((size_t)NTOK*256*4);
    float* vb    = (float*)alloc((size_t)NTOK*256*4);
    float* hres  = (float*)alloc((size_t)NTOK*HID_C*4);      // resid+attn, then +moe
    bf16*  h2b   = (bf16*)alloc((size_t)NTOK*HID_C*2);       // bf16 copy of norm2 out (MoE A)
    bf16*  inter = (bf16*)alloc((size_t)2*NTOK*INTER_C*2);   // 8192 x 2816
    float* attnb = h1;
    float* h2f   = qb;

    (void)hipMemsetAsync(cnt, 0, 64, stream);
    (void)hipMemsetAsync(psum, 0, 64, stream);

    rmsnorm_k<false><<<NTOK, 256, 0, stream>>>(hidden, n1w, h1, nullptr);
    sgemm_k<false><<<dim3(32, 8), 256, 0, stream>>>(h1, wq, qb, nullptr, 1024, 1024);
    sgemm_k<false><<<dim3(32, 2), 256, 0, stream>>>(h1, wk, kb, nullptr, 256, 1024);
    sgemm_k<false><<<dim3(32, 2), 256, 0, stream>>>(h1, wv, vb, nullptr, 256, 1024);
    rope_k<<<10240, 256, 0, stream>>>(qb, kb, fcos, fsin);
    attn_k<<<dim3(NTOK, 16), 64, 0, stream>>>(qb, kb, vb, attnb);
    sgemm_k<true><<<dim3(32, 8), 256, 0, stream>>>(attnb, wo, hres, hidden, 1024, 1024);
    rmsnorm_k<true><<<NTOK, 256, 0, stream>>>(hres, n2w, h2f, h2b);
    router_k<<<NTOK, 64, 0, stream>>>(h2f, routerw, lists, wl, cnt, psum);
    finalize_k<<<1, 64, 0, stream>>>(cnt, psum, offs, (float*)d_out);
    moe_mlp1_k<<<dim3(32, 44, 8), 256, 0, stream>>>(h2b, gatew, upw, inter, lists, cnt, offs);
    moe_mlp2_k<<<dim3(32, 8, 8), 256, 0, stream>>>(inter, downw, hres, wl, lists, cnt, offs);
    final_k<<<NTOK, 256, 0, stream>>>(hres, (float*)d_out);
}